// Round 1
// baseline (238.685 us; speedup 1.0000x reference)
//
#include <hip/hip_runtime.h>
#include <hip/hip_bf16.h>
#include <stdint.h>

// Problem constants
// B=4, S=2048, HDIM=1024, H=16, D=64, L=128, NB=16
// M = B*S = 8192 rows; N = H*D = 1024; K = HDIM = 1024
constexpr int GM = 8192;
constexpr int GK = 1024;
constexpr int GN = 1024;
constexpr size_t NACT = (size_t)GM * GN;      // 8388608 elements
constexpr int CHUNK = 32;                      // scan chunk length
constexpr int NCHUNK = 64;                     // 64*32 = 2048 = S
constexpr int NCH = 4096;                      // B*H*D channels

#define DEVINL __device__ __forceinline__

typedef __attribute__((ext_vector_type(8))) short bf16x8;
typedef __attribute__((ext_vector_type(4))) float f32x4;

DEVINL float sigmoidf_(float x) { return 1.0f / (1.0f + __expf(-x)); }

DEVINL unsigned short f2bf(float x) {
  unsigned int u = __builtin_bit_cast(unsigned int, x);
  unsigned int rnd = 0x7fffu + ((u >> 16) & 1u);
  return (unsigned short)((u + rnd) >> 16);
}
DEVINL float bf2f(unsigned short u) {
  unsigned int x = ((unsigned int)u) << 16;
  return __builtin_bit_cast(float, x);
}

DEVINL void gload16(const void* g, void* l) {
  __builtin_amdgcn_global_load_lds(
      (const __attribute__((address_space(1))) unsigned int*)g,
      (__attribute__((address_space(3))) unsigned int*)l, 16, 0, 0);
}

// ---------------- prep: f32 -> bf16 convert (vectorized) ----------------
__global__ void cvt_bf16_kernel(const float* __restrict__ src,
                                unsigned short* __restrict__ dst, int n4) {
  int i = blockIdx.x * blockDim.x + threadIdx.x;
  int stride = gridDim.x * blockDim.x;
  for (; i < n4; i += stride) {
    float4 v = ((const float4*)src)[i];
    ushort4 o;
    o.x = f2bf(v.x); o.y = f2bf(v.y); o.z = f2bf(v.z); o.w = f2bf(v.w);
    ((ushort4*)dst)[i] = o;
  }
}

// ---------------- prep: transpose 1024x1024 f32 -> bf16 (Wt[n][k]) ----------------
__global__ void transpose_cvt_kernel(const float* __restrict__ W,
                                     unsigned short* __restrict__ Wt) {
  __shared__ float tile[32][33];
  int n0 = blockIdx.x * 32, k0 = blockIdx.y * 32;
  int tx = threadIdx.x & 31, ty = threadIdx.x >> 5;  // 32x8
#pragma unroll
  for (int i = 0; i < 32; i += 8)
    tile[ty + i][tx] = W[(size_t)(k0 + ty + i) * GN + n0 + tx];
  __syncthreads();
#pragma unroll
  for (int i = 0; i < 32; i += 8)
    Wt[(size_t)(n0 + ty + i) * GK + k0 + tx] = f2bf(tile[tx][ty + i]);
}

// ---------------- MFMA GEMM: 128x128 tile, BK=32, 4 waves ----------------
// MODE 0: f gate  -> bf16 sigmoid(x + bias + 1)
// MODE 1: o gate  -> bf16 sigmoid(x + bias)
// MODE 2: u gate  -> bf16 sigmoid(x1+b1)*tanh(x2+b2)  (two K-loops)
// MODE 3: y proj  -> f32  x + bias
template <int MODE>
__global__ __launch_bounds__(256) void gemm128(
    const unsigned short* __restrict__ A1, const unsigned short* __restrict__ W1,
    const float* __restrict__ bias1,
    const unsigned short* __restrict__ A2, const unsigned short* __restrict__ W2,
    const float* __restrict__ bias2,
    unsigned short* __restrict__ outb, float* __restrict__ outf) {
  __shared__ __align__(16) unsigned short As[128 * 32];
  __shared__ __align__(16) unsigned short Bs[128 * 32];
  const int tid = threadIdx.x;
  const int wave = tid >> 6, lane = tid & 63;
  const int bm = blockIdx.x, bn = blockIdx.y;
  const int wm = (wave >> 1) * 64, wn = (wave & 1) * 64;
  const int lrow = lane & 15, lko = (lane >> 4) * 8;
  const int srow = tid >> 2, scol = (tid & 3) * 8;  // staging: 4 lanes x 16B per row

  f32x4 acc1[4][4];
  f32x4 acc2[4][4];
#pragma unroll
  for (int m = 0; m < 4; ++m)
#pragma unroll
    for (int n = 0; n < 4; ++n) {
      acc1[m][n] = (f32x4){0.f, 0.f, 0.f, 0.f};
      acc2[m][n] = (f32x4){0.f, 0.f, 0.f, 0.f};
    }

  auto run = [&](const unsigned short* __restrict__ A,
                 const unsigned short* __restrict__ W, f32x4(&acc)[4][4]) {
    for (int k0 = 0; k0 < GK; k0 += 32) {
      __syncthreads();  // previous tile's reads done
      gload16(A + (size_t)(bm * 128 + srow) * GK + k0 + scol,
              (char*)As + wave * 1024);
      gload16(A + (size_t)(bm * 128 + 64 + srow) * GK + k0 + scol,
              (char*)As + 4096 + wave * 1024);
      gload16(W + (size_t)(bn * 128 + srow) * GK + k0 + scol,
              (char*)Bs + wave * 1024);
      gload16(W + (size_t)(bn * 128 + 64 + srow) * GK + k0 + scol,
              (char*)Bs + 4096 + wave * 1024);
      __syncthreads();  // barrier drains vmcnt -> LDS tile ready

      bf16x8 af[4], bfr[4];
#pragma unroll
      for (int m = 0; m < 4; ++m)
        af[m] = *(const bf16x8*)&As[(wm + m * 16 + lrow) * 32 + lko];
#pragma unroll
      for (int n = 0; n < 4; ++n)
        bfr[n] = *(const bf16x8*)&Bs[(wn + n * 16 + lrow) * 32 + lko];
#pragma unroll
      for (int m = 0; m < 4; ++m)
#pragma unroll
        for (int n = 0; n < 4; ++n)
          acc[m][n] = __builtin_amdgcn_mfma_f32_16x16x32_bf16(af[m], bfr[n],
                                                              acc[m][n], 0, 0, 0);
    }
  };

  run(A1, W1, acc1);
  if constexpr (MODE == 2) run(A2, W2, acc2);

  float b1v[4], b2v[4];
#pragma unroll
  for (int n = 0; n < 4; ++n) {
    int gc = bn * 128 + wn + n * 16 + lrow;
    b1v[n] = bias1[gc];
    if constexpr (MODE == 2) b2v[n] = bias2[gc];
    else b2v[n] = 0.f;
  }

#pragma unroll
  for (int m = 0; m < 4; ++m) {
#pragma unroll
    for (int n = 0; n < 4; ++n) {
      int gc = bn * 128 + wn + n * 16 + lrow;
#pragma unroll
      for (int j = 0; j < 4; ++j) {
        int gr = bm * 128 + wm + m * 16 + (lane >> 4) * 4 + j;
        float v = acc1[m][n][j] + b1v[n];
        size_t oidx = (size_t)gr * GN + gc;
        if constexpr (MODE == 0) {
          outb[oidx] = f2bf(sigmoidf_(v + 1.0f));
        } else if constexpr (MODE == 1) {
          outb[oidx] = f2bf(sigmoidf_(v));
        } else if constexpr (MODE == 2) {
          float v2 = acc2[m][n][j] + b2v[n];
          outb[oidx] = f2bf(sigmoidf_(v) * tanhf(v2));
        } else {
          outf[oidx] = v;
        }
      }
    }
  }
}

// ---------------- scan phase A: per-chunk (prod f, local c) ----------------
__global__ void scan_phaseA_kernel(const unsigned short* __restrict__ F,
                                   const unsigned short* __restrict__ U,
                                   float* __restrict__ Pt, float* __restrict__ Ct) {
  int tid = blockIdx.x * blockDim.x + threadIdx.x;  // NCH * NCHUNK = 262144
  int ch = tid & (NCH - 1), chunk = tid >> 12;
  int b = ch >> 10, n = ch & 1023;
  size_t base = ((size_t)(b * 2048 + chunk * CHUNK)) * 1024 + n;
  float c = 0.f, P = 1.f;
#pragma unroll 8
  for (int t = 0; t < CHUNK; ++t) {
    size_t idx = base + (size_t)t * 1024;
    float f = bf2f(F[idx]);
    float u = bf2f(U[idx]);
    c = __builtin_fmaf(f, c, u);
    P *= f;
  }
  Pt[tid] = P;
  Ct[tid] = c;
}

// ---------------- scan combine: sequential over 64 chunks ----------------
__global__ void scan_combine_kernel(const float* __restrict__ Pt,
                                    const float* __restrict__ Ct,
                                    const float* __restrict__ c0,
                                    float* __restrict__ Cin,
                                    float* __restrict__ last_c) {
  int ch = blockIdx.x * blockDim.x + threadIdx.x;  // 4096
  float c = c0[ch];
#pragma unroll
  for (int j = 0; j < NCHUNK; ++j) {
    Cin[j * NCH + ch] = c;
    c = __builtin_fmaf(Pt[j * NCH + ch], c, Ct[j * NCH + ch]);
  }
  last_c[ch] = c;
}

// ---------------- scan phase C: replay with carry, emit h ----------------
__global__ void scan_phaseC_kernel(const unsigned short* __restrict__ F,
                                   const unsigned short* __restrict__ U,
                                   const unsigned short* __restrict__ O,
                                   const float* __restrict__ Cin,
                                   unsigned short* __restrict__ Hb,
                                   float* __restrict__ last_h) {
  int tid = blockIdx.x * blockDim.x + threadIdx.x;
  int ch = tid & (NCH - 1), chunk = tid >> 12;
  int b = ch >> 10, n = ch & 1023;
  size_t base = ((size_t)(b * 2048 + chunk * CHUNK)) * 1024 + n;
  float c = Cin[tid];  // tid == chunk*NCH + ch
  float h = 0.f;
#pragma unroll 8
  for (int t = 0; t < CHUNK; ++t) {
    size_t idx = base + (size_t)t * 1024;
    float f = bf2f(F[idx]);
    float u = bf2f(U[idx]);
    float o = bf2f(O[idx]);
    c = __builtin_fmaf(f, c, u);
    h = o * tanhf(c);
    Hb[idx] = f2bf(h);
  }
  if (chunk == NCHUNK - 1) last_h[ch] = h;
}

extern "C" void kernel_launch(void* const* d_in, const int* in_sizes, int n_in,
                              void* d_out, int out_size, void* d_ws, size_t ws_size,
                              hipStream_t stream) {
  const float* f_in = (const float*)d_in[0];
  const float* i_in = (const float*)d_in[1];
  const float* z_in = (const float*)d_in[2];
  const float* o_in = (const float*)d_in[3];
  const float* c0 = (const float*)d_in[4];
  // d_in[5] = h0 (unused by reference)
  const float* Wf = (const float*)d_in[6];
  const float* bf_ = (const float*)d_in[7];
  const float* Wi = (const float*)d_in[8];
  const float* bi = (const float*)d_in[9];
  const float* Wz = (const float*)d_in[10];
  const float* bz = (const float*)d_in[11];
  const float* Wo = (const float*)d_in[12];
  const float* bo = (const float*)d_in[13];
  const float* Wp = (const float*)d_in[14];
  const float* bp = (const float*)d_in[15];

  float* y = (float*)d_out;
  float* last_c = y + NACT;
  float* last_h = last_c + NCH;

  // workspace carve (all 256B-aligned by construction)
  char* w = (char*)d_ws;
  const size_t ABYTES = NACT * 2;            // 16 MiB
  const size_t WBYTES = (size_t)GK * GN * 2; // 2 MiB
  unsigned short* Af = (unsigned short*)(w + 0 * ABYTES);
  unsigned short* Ai = (unsigned short*)(w + 1 * ABYTES);
  unsigned short* Az = (unsigned short*)(w + 2 * ABYTES);
  unsigned short* Ao = (unsigned short*)(w + 3 * ABYTES);
  char* wt = w + 4 * ABYTES;
  unsigned short* Wtf = (unsigned short*)(wt + 0 * WBYTES);
  unsigned short* Wti = (unsigned short*)(wt + 1 * WBYTES);
  unsigned short* Wtz = (unsigned short*)(wt + 2 * WBYTES);
  unsigned short* Wto = (unsigned short*)(wt + 3 * WBYTES);
  unsigned short* Wtp = (unsigned short*)(wt + 4 * WBYTES);
  char* gp = wt + 5 * WBYTES;
  unsigned short* F = (unsigned short*)(gp + 0 * ABYTES);
  unsigned short* U = (unsigned short*)(gp + 1 * ABYTES);
  unsigned short* O = (unsigned short*)(gp + 2 * ABYTES);
  unsigned short* Hb = (unsigned short*)(gp + 3 * ABYTES);
  char* sp = gp + 4 * ABYTES;
  const size_t SBYTES = (size_t)NCH * NCHUNK * 4;  // 1 MiB
  float* Pt = (float*)(sp + 0 * SBYTES);
  float* Ct = (float*)(sp + 1 * SBYTES);
  float* Cin = (float*)(sp + 2 * SBYTES);

  // 1) convert activations to bf16
  const int n4 = (int)(NACT / 4);
  cvt_bf16_kernel<<<2048, 256, 0, stream>>>(f_in, Af, n4);
  cvt_bf16_kernel<<<2048, 256, 0, stream>>>(i_in, Ai, n4);
  cvt_bf16_kernel<<<2048, 256, 0, stream>>>(z_in, Az, n4);
  cvt_bf16_kernel<<<2048, 256, 0, stream>>>(o_in, Ao, n4);

  // 2) transpose+convert weights -> Wt[n][k] bf16
  dim3 tg(32, 32);
  transpose_cvt_kernel<<<tg, 256, 0, stream>>>(Wf, Wtf);
  transpose_cvt_kernel<<<tg, 256, 0, stream>>>(Wi, Wti);
  transpose_cvt_kernel<<<tg, 256, 0, stream>>>(Wz, Wtz);
  transpose_cvt_kernel<<<tg, 256, 0, stream>>>(Wo, Wto);
  transpose_cvt_kernel<<<tg, 256, 0, stream>>>(Wp, Wtp);

  // 3) gate GEMMs with fused activations
  dim3 gg(GM / 128, GN / 128);
  gemm128<0><<<gg, 256, 0, stream>>>(Af, Wtf, bf_, nullptr, nullptr, nullptr, F, nullptr);
  gemm128<1><<<gg, 256, 0, stream>>>(Ao, Wto, bo, nullptr, nullptr, nullptr, O, nullptr);
  gemm128<2><<<gg, 256, 0, stream>>>(Ai, Wti, bi, Az, Wtz, bz, U, nullptr);

  // 4) chunked linear-recurrence scan
  scan_phaseA_kernel<<<(NCH * NCHUNK) / 256, 256, 0, stream>>>(F, U, Pt, Ct);
  scan_combine_kernel<<<NCH / 256, 256, 0, stream>>>(Pt, Ct, c0, Cin, last_c);
  scan_phaseC_kernel<<<(NCH * NCHUNK) / 256, 256, 0, stream>>>(F, U, O, Cin, Hb, last_h);

  // 5) output projection
  gemm128<3><<<gg, 256, 0, stream>>>(Hb, Wtp, bp, nullptr, nullptr, nullptr, nullptr, y);
}